// Round 1
// baseline (1024.166 us; speedup 1.0000x reference)
//
#include <hip/hip_runtime.h>
#include <math.h>

// ---------------- workspace layout (in floats) ----------------
#define WS_XP   0
#define N_XP    (8*60*60*64)          // padded NHWC x, pad=2 both convs
#define WS_WOFF (WS_XP + N_XP)
#define N_WOFF  (25*64*104)           // packed offset-conv weights [kk][c][104]
#define WS_W3P  (WS_WOFF + N_WOFF)
#define N_W3P   (9*64*128)            // packed w3 [kk][c][128]
#define WS_W5P  (WS_W3P + N_W3P)
#define N_W5P   (25*64*128)           // packed w5 [kk][c][128]
#define WS_WSUB (WS_W5P + N_W5P)
#define N_WSUB  (64*128)              // packed sub_w [c][128]
#define WS_BOM  (WS_WSUB + N_WSUB)
#define N_BOM   104                   // packed offset-conv bias
#define WS_OM   (WS_BOM + N_BOM)
#define N_OM    (8*104*3136)          // offset maps, NCHW (B,104,3136)
#define WS_XS   (WS_OM + N_OM)
#define N_XS    (8*128*3136)          // 1x1-conv residual, NCHW
// total = 8,116,840 floats = 32.5 MB

// ---------------- prep: pad/transpose x + pack weights ----------------
__global__ void prep_kernel(const float* __restrict__ xin,
                            const float* __restrict__ w3,
                            const float* __restrict__ off3w, const float* __restrict__ off3b,
                            const float* __restrict__ w5,
                            const float* __restrict__ off5w, const float* __restrict__ off5b,
                            const float* __restrict__ subw,
                            float* __restrict__ ws)
{
    const int NTOT = WS_BOM + N_BOM;
    for (int i = blockIdx.x * 256 + threadIdx.x; i < NTOT; i += gridDim.x * 256) {
        float v = 0.f;
        if (i < WS_WOFF) {                       // padded NHWC x
            int c = i & 63; int t = i >> 6;
            int xx = t % 60; t /= 60;
            int yy = t % 60; int b = t / 60;
            int y = yy - 2, x = xx - 2;
            if ((unsigned)y < 56u && (unsigned)x < 56u)
                v = xin[((b*64 + c)*56 + y)*56 + x];
        } else if (i < WS_W3P) {                 // offset weights -> [kk][c][104]
            int j = i - WS_WOFF;
            int o = j % 104; int t = j / 104;
            int c = t & 63;  int kk = t >> 6;    // kk in 0..24 (5x5 grid)
            if (o < 27) {                        // 3x3 kernel embedded in inner 3x3
                int ky = kk / 5, kx = kk % 5;
                if (ky >= 1 && ky <= 3 && kx >= 1 && kx <= 3)
                    v = off3w[((o*64 + c)*3 + (ky-1))*3 + (kx-1)];
            } else if (o < 102) {
                v = off5w[((o-27)*64 + c)*25 + kk];
            }
        } else if (i < WS_W5P) {                 // w3 -> [kk][c][128]
            int j = i - WS_W3P;
            int o = j & 127; int t = j >> 7;
            int c = t & 63;  int kk = t >> 6;    // 0..8
            v = w3[(o*64 + c)*9 + kk];
        } else if (i < WS_WSUB) {                // w5 -> [kk][c][128]
            int j = i - WS_W5P;
            int o = j & 127; int t = j >> 7;
            int c = t & 63;  int kk = t >> 6;    // 0..24
            v = w5[(o*64 + c)*25 + kk];
        } else if (i < WS_BOM) {                 // sub_w -> [c][128]
            int j = i - WS_WSUB;
            int o = j & 127; int c = j >> 7;
            v = subw[o*64 + c];
        } else {                                 // packed offset bias
            int j = i - WS_BOM;
            v = (j < 27) ? off3b[j] : ((j < 102) ? off5b[j-27] : 0.f);
        }
        ws[i] = v;
    }
}

// ---------------- unified implicit-GEMM conv ----------------
// Block: 64 flat pixels x (4 waves * OCW channels). Per tap:
//   Phase A: build cols[px][c] in LDS (lane = channel, coalesced NHWC reads,
//            bilinear+mask for DEFORM; wave-uniform offset math)
//   Phase B: GEMM: 1 ds_read feeds OCW FMAs; weights wave-uniform -> s_load
template<int OCW, bool DEFORM, bool FUSE>
__global__ __launch_bounds__(256) void convk(
    const float* __restrict__ xp,     // (B,60,60,64) padded NHWC
    const float* __restrict__ om,     // (B,104,3136) or unused
    const float* __restrict__ xsb,    // (B,128,3136) or unused
    float* __restrict__ out,
    const float* __restrict__ wpA, const float* __restrict__ biasA,
    const float* __restrict__ wpB, const float* __restrict__ biasB,
    int ksA, int ksB, int padA, int padB,
    int omc0A, int omc0B, int outc0A, int outc0B,
    int wstride, int out_cstride)
{
    const int z = blockIdx.z;
    const float* wp   = z ? wpB : wpA;
    const float* bias = z ? biasB : biasA;
    const int KS    = z ? ksB : ksA;
    const int PAD   = z ? padB : padA;
    const int omc0  = z ? omc0B : omc0A;
    const int outc0 = z ? outc0B : outc0A;
    const int K2 = KS * KS;
    const int SHIFT = 2 - PAD;        // pad-k coords -> pad-2 array coords
    const int HP = 56 + 2 * PAD;      // valid range bound (square)

    const int b    = blockIdx.y;
    const int pix0 = blockIdx.x * 64;
    const int lane = threadIdx.x & 63;
    const int wave = threadIdx.x >> 6;

    __shared__ float cols[64 * 65];   // [px][c], stride 65 -> conflict-free

    float acc[OCW];
#pragma unroll
    for (int j = 0; j < OCW; ++j) acc[j] = 0.f;

    const float* xpb = xp + b * (60 * 60 * 64);
    const int wbase = __builtin_amdgcn_readfirstlane(wave * OCW);

    for (int kk = 0; kk < K2; ++kk) {
        const int ky = kk / KS;
        const int kx = kk - ky * KS;
        __syncthreads();
        // ---- Phase A: build cols for this tap ----
        for (int it = 0; it < 16; ++it) {
            const int px  = wave * 16 + it;
            const int pix = pix0 + px;
            const int oy  = pix / 56;
            const int ox  = pix - oy * 56;
            float v;
            if (DEFORM) {
                const float dy = om[(b*104 + omc0 + kk)         * 3136 + pix];
                const float dx = om[(b*104 + omc0 + K2 + kk)    * 3136 + pix];
                const float ml = om[(b*104 + omc0 + 2*K2 + kk)  * 3136 + pix];
                const float mask = 1.f / (1.f + __expf(-ml));
                const float py = (float)(oy + ky) + dy;   // pad-k coords
                const float qx = (float)(ox + kx) + dx;
                const float y0f = floorf(py), x0f = floorf(qx);
                const float ty = py - y0f, tx = qx - x0f;
                const int y0 = (int)y0f, x0 = (int)x0f;
                const int y1 = y0 + 1,   x1 = x0 + 1;
                float w00 = (1.f - ty) * (1.f - tx) * mask;
                float w01 = (1.f - ty) * tx * mask;
                float w10 = ty * (1.f - tx) * mask;
                float w11 = ty * tx * mask;
                const bool vy0 = (y0 >= 0) && (y0 < HP);
                const bool vy1 = (y1 >= 0) && (y1 < HP);
                const bool vx0 = (x0 >= 0) && (x0 < HP);
                const bool vx1 = (x1 >= 0) && (x1 < HP);
                if (!(vy0 && vx0)) w00 = 0.f;
                if (!(vy0 && vx1)) w01 = 0.f;
                if (!(vy1 && vx0)) w10 = 0.f;
                if (!(vy1 && vx1)) w11 = 0.f;
                const int yc0 = min(max(y0, 0), HP-1) + SHIFT;
                const int yc1 = min(max(y1, 0), HP-1) + SHIFT;
                const int xc0 = min(max(x0, 0), HP-1) + SHIFT;
                const int xc1 = min(max(x1, 0), HP-1) + SHIFT;
                const float v00 = xpb[(yc0*60 + xc0)*64 + lane];
                const float v01 = xpb[(yc0*60 + xc1)*64 + lane];
                const float v10 = xpb[(yc1*60 + xc0)*64 + lane];
                const float v11 = xpb[(yc1*60 + xc1)*64 + lane];
                v = v00*w00 + v01*w01 + v10*w10 + v11*w11;
            } else {
                const int yy = oy + ky + SHIFT;
                const int xx = ox + kx + SHIFT;
                v = xpb[(yy*60 + xx)*64 + lane];
            }
            cols[px * 65 + lane] = v;
        }
        __syncthreads();
        // ---- Phase B: GEMM for this tap ----
        const float* wkk = wp + kk * 64 * wstride + wbase;
        for (int c = 0; c < 64; ++c) {
            const float xv = cols[lane * 65 + c];
            const float* wrow = wkk + c * wstride;
#pragma unroll
            for (int j = 0; j < OCW; ++j)
                acc[j] = fmaf(xv, wrow[j], acc[j]);
        }
    }
    // ---- epilogue: bias (+xs, relu) + store ----
    const int pix = pix0 + lane;
#pragma unroll
    for (int j = 0; j < OCW; ++j) {
        const int o = wbase + j;
        float v = acc[j] + bias[o];
        if (FUSE) {
            v += xsb[(b*128 + o)*3136 + pix];
            v = fmaxf(v, 0.f);
        }
        out[(b * out_cstride + outc0 + o) * 3136 + pix] = v;
    }
}

// ---------------- launch ----------------
extern "C" void kernel_launch(void* const* d_in, const int* in_sizes, int n_in,
                              void* d_out, int out_size, void* d_ws, size_t ws_size,
                              hipStream_t stream)
{
    (void)in_sizes; (void)n_in; (void)out_size; (void)ws_size;
    const float* x     = (const float*)d_in[0];
    const float* w3    = (const float*)d_in[1];
    const float* b3    = (const float*)d_in[2];
    const float* off3w = (const float*)d_in[3];
    const float* off3b = (const float*)d_in[4];
    const float* w5    = (const float*)d_in[5];
    const float* b5    = (const float*)d_in[6];
    const float* off5w = (const float*)d_in[7];
    const float* off5b = (const float*)d_in[8];
    const float* subw  = (const float*)d_in[9];
    const float* subb  = (const float*)d_in[10];
    float* ws  = (float*)d_ws;
    float* out = (float*)d_out;

    prep_kernel<<<dim3(2048), dim3(256), 0, stream>>>(
        x, w3, off3w, off3b, w5, off5w, off5b, subw, ws);

    const float* xp   = ws + WS_XP;
    const float* woff = ws + WS_WOFF;
    const float* w3p  = ws + WS_W3P;
    const float* w5p  = ws + WS_W5P;
    const float* wsub = ws + WS_WSUB;
    const float* bom  = ws + WS_BOM;
    float* omb = ws + WS_OM;
    float* xsb = ws + WS_XS;

    // 1x1 residual conv -> xs buffer
    convk<32, false, false><<<dim3(49, 8, 1), dim3(256), 0, stream>>>(
        xp, nullptr, nullptr, xsb,
        wsub, subb, wsub, subb,
        1, 1, 0, 0, 0, 0, 0, 0,
        128, 128);

    // offset conv (102ch padded to 104), split into two column halves via z
    convk<13, false, false><<<dim3(49, 8, 2), dim3(256), 0, stream>>>(
        xp, nullptr, nullptr, omb,
        woff, bom, woff + 52, bom + 52,
        5, 5, 2, 2, 0, 0, 0, 52,
        104, 104);

    // deformable convs: z=0 -> k3 (out ch 0..127), z=1 -> k5 (out ch 128..255)
    convk<32, true, true><<<dim3(49, 8, 2), dim3(256), 0, stream>>>(
        xp, omb, xsb, out,
        w3p, b3, w5p, b5,
        3, 5, 1, 2, 0, 27, 0, 128,
        128, 256);
}

// Round 2
// 186.964 us; speedup vs baseline: 5.4779x; 5.4779x over previous
//
#include <hip/hip_runtime.h>
#include <math.h>

typedef __attribute__((ext_vector_type(8))) short short8;
typedef __attribute__((ext_vector_type(4))) float f32x4;

// ---------------- workspace layout ----------------
// ushort region (bf16 data), element offsets:
#define US_XP    0
#define N_XP     (8*60*60*64)            // padded NHWC x, pad=2, bf16
#define US_WOFF  (US_XP + N_XP)          // offset-conv weights, A-frag order
#define N_WOFF   (25*2*8*64*8)
#define US_W5    (US_WOFF + N_WOFF)      // w5 + sub tap (26 taps)
#define N_W5     (26*2*8*64*8)
#define US_W3    (US_W5 + N_W5)          // w3 + sub tap (10 taps)
#define N_W3     (10*2*8*64*8)
#define US_TOT   (US_W3 + N_W3)
// float region, byte-aligned after ushort region:
#define FB_BYTES (((US_TOT*2) + 15) & ~15)
#define F_BOM    0                       // offset-conv bias (128, padded)
#define F_B5     128                     // b5 + sub_b
#define F_B3     256                     // b3 + sub_b
#define F_OM     384                     // offset maps (8,128,3136) fp32
#define N_OM     (8*128*3136)

__device__ __forceinline__ unsigned short f2bf(float f) {
    union { float f; unsigned u; } v; v.f = f;
    unsigned r = v.u + 0x7FFFu + ((v.u >> 16) & 1u);
    return (unsigned short)(r >> 16);
}
__device__ __forceinline__ float bf2f(unsigned short u) {
    union { unsigned u; float f; } v; v.u = ((unsigned)u) << 16; return v.f;
}

// ---------------- prep: pad x (bf16 NHWC) + pack weights into A-frag order ----------------
// A-frag (16x16x32 bf16): lane l holds A[oc = l&15][c = (l>>4)*8 + j], j=0..7.
// Packed index: ((((tap*2 + kt)*8 + oct)*64 + lane)*8 + j)
__global__ __launch_bounds__(256) void prep_kernel(
    const float* __restrict__ x,
    const float* __restrict__ w3, const float* __restrict__ b3,
    const float* __restrict__ off3w, const float* __restrict__ off3b,
    const float* __restrict__ w5, const float* __restrict__ b5,
    const float* __restrict__ off5w, const float* __restrict__ off5b,
    const float* __restrict__ subw, const float* __restrict__ subb,
    unsigned short* __restrict__ us, float* __restrict__ fb)
{
    const int NTOT = US_TOT + 384;
    for (int i = blockIdx.x*256 + threadIdx.x; i < NTOT; i += gridDim.x*256) {
        if (i < US_TOT) {
            float v = 0.f;
            if (i < US_WOFF) {                      // padded bf16 NHWC x
                int c = i & 63, t = i >> 6;
                int xx = t % 60; t /= 60;
                int yy = t % 60; int b = t / 60;
                int y = yy - 2, xc = xx - 2;
                if ((unsigned)y < 56u && (unsigned)xc < 56u)
                    v = x[((b*64 + c)*56 + y)*56 + xc];
            } else {
                int j, mode;
                if (i < US_W5)      { j = i - US_WOFF; mode = 0; }
                else if (i < US_W3) { j = i - US_W5;   mode = 1; }
                else                { j = i - US_W3;   mode = 2; }
                int j8   = j & 7;
                int lane = (j >> 3) & 63;
                int oct  = (j >> 9) & 7;
                int kt   = (j >> 12) & 1;
                int tap  = j >> 13;
                int oc   = oct*16 + (lane & 15);
                int c    = kt*32 + (lane >> 4)*8 + j8;
                if (mode == 0) {                    // offset conv (5x5, k3 embedded center)
                    if (oc < 27) {
                        int ky = tap/5, kx = tap%5;
                        if (ky>=1 && ky<=3 && kx>=1 && kx<=3)
                            v = off3w[((oc*64 + c)*3 + (ky-1))*3 + (kx-1)];
                    } else if (oc < 102) {
                        v = off5w[((oc-27)*64 + c)*25 + tap];
                    }
                } else if (mode == 1) {             // w5 (25) + sub tap
                    v = (tap < 25) ? w5[(oc*64 + c)*25 + tap] : subw[oc*64 + c];
                } else {                            // w3 (9) + sub tap
                    v = (tap < 9) ? w3[(oc*64 + c)*9 + tap] : subw[oc*64 + c];
                }
            }
            us[i] = f2bf(v);
        } else {
            int fj = i - US_TOT;
            float v;
            if (fj < 128)      v = (fj < 27) ? off3b[fj] : ((fj < 102) ? off5b[fj-27] : 0.f);
            else if (fj < 256) { int o = fj-128; v = b5[o] + subb[o]; }
            else               { int o = fj-256; v = b3[o] + subb[o]; }
            fb[fj] = v;
        }
    }
}

// ---------------- MFMA conv: 32 px x 128 oc per block, K = ntaps*64 ----------------
// Per tap: Phase A builds cols[px][c] bf16 in LDS (double-buffered, 1 barrier/tap),
// Phase B: 8 MFMAs/wave (A=weights m=oc, B=cols n=px), fp32 accum.
template<bool DEFORM>
__global__ __launch_bounds__(256, 3) void convm(
    const unsigned short* __restrict__ xp,   // bf16 (B,60,60,64)
    const float* __restrict__ om,            // (B,128,3136) fp32 offset maps
    float* __restrict__ out,
    const unsigned short* __restrict__ wpA, const float* __restrict__ biasA,
    const unsigned short* __restrict__ wpB, const float* __restrict__ biasB,
    int ksA, int ksB, int ntA, int ntB, int omc0A, int omc0B,
    int outc0A, int outc0B, int out_cs)
{
    const int z = blockIdx.z;
    const unsigned short* wp = z ? wpB : wpA;
    const float* bias = z ? biasB : biasA;
    const int KS    = z ? ksB : ksA;
    const int ntaps = z ? ntB : ntA;
    const int omc0  = z ? omc0B : omc0A;
    const int outc0 = z ? outc0B : outc0A;
    const int K2 = KS*KS;
    const int PAD = (KS == 3) ? 1 : 2;
    const int SHIFT = 2 - PAD;            // pad-KS coords -> pad-2 array coords
    const int HP = 56 + 2*PAD;

    const int b    = blockIdx.y;
    const int pix0 = blockIdx.x * 32;
    const int lane = threadIdx.x & 63;
    const int wave = threadIdx.x >> 6;
    const int r15  = lane & 15;
    const int q4   = lane >> 4;

    __shared__ unsigned short cols[2][32*72];   // stride 72 -> 16B-aligned frag reads

    f32x4 acc[2][2] = {{{0.f,0.f,0.f,0.f},{0.f,0.f,0.f,0.f}},
                       {{0.f,0.f,0.f,0.f},{0.f,0.f,0.f,0.f}}};

    const unsigned short* xpb = xp + (size_t)b * (60*60*64);

    auto stage = [&](int tap, unsigned short* buf) {
        const int cl = r15 * 4;               // 4 channels per lane
        int ky = 0, kx = 0;
        if (tap < K2) { ky = tap / KS; kx = tap - ky*KS; }
#pragma unroll
        for (int it = 0; it < 2; ++it) {
            const int px  = wave*8 + it*4 + q4;
            const int pix = pix0 + px;
            const int oy  = pix / 56;
            const int ox  = pix - oy*56;
            ushort4 val;
            if (DEFORM && tap < K2) {
                const float dy = om[(size_t)(b*128 + omc0 + tap)*3136 + pix];
                const float dx = om[(size_t)(b*128 + omc0 + K2 + tap)*3136 + pix];
                const float ml = om[(size_t)(b*128 + omc0 + 2*K2 + tap)*3136 + pix];
                const float mask = 1.f / (1.f + __expf(-ml));
                const float py = (float)(oy + ky) + dy;
                const float qx = (float)(ox + kx) + dx;
                const float y0f = floorf(py), x0f = floorf(qx);
                const float ty = py - y0f, tx = qx - x0f;
                const int y0 = (int)y0f, x0 = (int)x0f;
                const int y1 = y0 + 1,   x1 = x0 + 1;
                float w00 = (1.f-ty)*(1.f-tx)*mask;
                float w01 = (1.f-ty)*tx*mask;
                float w10 = ty*(1.f-tx)*mask;
                float w11 = ty*tx*mask;
                const bool vy0 = (y0>=0)&(y0<HP), vy1 = (y1>=0)&(y1<HP);
                const bool vx0 = (x0>=0)&(x0<HP), vx1 = (x1>=0)&(x1<HP);
                if (!(vy0&vx0)) w00 = 0.f;
                if (!(vy0&vx1)) w01 = 0.f;
                if (!(vy1&vx0)) w10 = 0.f;
                if (!(vy1&vx1)) w11 = 0.f;
                const int yc0 = min(max(y0,0),HP-1)+SHIFT;
                const int yc1 = min(max(y1,0),HP-1)+SHIFT;
                const int xc0 = min(max(x0,0),HP-1)+SHIFT;
                const int xc1 = min(max(x1,0),HP-1)+SHIFT;
                ushort4 u00 = *(const ushort4*)(xpb + (yc0*60+xc0)*64 + cl);
                ushort4 u01 = *(const ushort4*)(xpb + (yc0*60+xc1)*64 + cl);
                ushort4 u10 = *(const ushort4*)(xpb + (yc1*60+xc0)*64 + cl);
                ushort4 u11 = *(const ushort4*)(xpb + (yc1*60+xc1)*64 + cl);
                val.x = f2bf(bf2f(u00.x)*w00 + bf2f(u01.x)*w01 + bf2f(u10.x)*w10 + bf2f(u11.x)*w11);
                val.y = f2bf(bf2f(u00.y)*w00 + bf2f(u01.y)*w01 + bf2f(u10.y)*w10 + bf2f(u11.y)*w11);
                val.z = f2bf(bf2f(u00.z)*w00 + bf2f(u01.z)*w01 + bf2f(u10.z)*w10 + bf2f(u11.z)*w11);
                val.w = f2bf(bf2f(u00.w)*w00 + bf2f(u01.w)*w01 + bf2f(u10.w)*w10 + bf2f(u11.w)*w11);
            } else {
                int yy, xx;
                if (DEFORM) { yy = oy + 2; xx = ox + 2; }              // sub-conv tap (1x1 center)
                else        { yy = oy + ky + SHIFT; xx = ox + kx + SHIFT; } // plain conv tap
                val = *(const ushort4*)(xpb + (yy*60+xx)*64 + cl);
            }
            *(ushort4*)&buf[px*72 + cl] = val;
        }
    };

    auto gemm = [&](int tap, const unsigned short* buf) {
#pragma unroll
        for (int kt = 0; kt < 2; ++kt) {
            const unsigned short* wt = wp + ((size_t)((tap*2 + kt)*8 + wave*2)*64 + lane)*8;
            short8 a0 = *(const short8*)wt;            // octile 2*wave
            short8 a1 = *(const short8*)(wt + 64*8);   // octile 2*wave+1
            const unsigned short* bp = buf + r15*72 + kt*32 + q4*8;
            short8 b0 = *(const short8*)bp;            // px tile 0
            short8 b1 = *(const short8*)(bp + 16*72);  // px tile 1
            acc[0][0] = __builtin_amdgcn_mfma_f32_16x16x32_bf16(a0, b0, acc[0][0], 0, 0, 0);
            acc[1][0] = __builtin_amdgcn_mfma_f32_16x16x32_bf16(a1, b0, acc[1][0], 0, 0, 0);
            acc[0][1] = __builtin_amdgcn_mfma_f32_16x16x32_bf16(a0, b1, acc[0][1], 0, 0, 0);
            acc[1][1] = __builtin_amdgcn_mfma_f32_16x16x32_bf16(a1, b1, acc[1][1], 0, 0, 0);
        }
    };

    stage(0, cols[0]);
    __syncthreads();
    for (int t = 0; t < ntaps; ++t) {
        if (t + 1 < ntaps) stage(t + 1, cols[(t+1) & 1]);
        gemm(t, cols[t & 1]);
        __syncthreads();
    }

    // epilogue: D[row=oc_local][col=px_local], row=(lane>>4)*4+reg, col=lane&15
#pragma unroll
    for (int j = 0; j < 2; ++j) {
#pragma unroll
        for (int pt = 0; pt < 2; ++pt) {
#pragma unroll
            for (int reg = 0; reg < 4; ++reg) {
                const int oc  = (wave*2 + j)*16 + q4*4 + reg;
                const int pix = pix0 + pt*16 + r15;
                float v = acc[j][pt][reg] + bias[oc];
                if (DEFORM) v = fmaxf(v, 0.f);
                out[((size_t)b*out_cs + outc0 + oc)*3136 + pix] = v;
            }
        }
    }
}

// ---------------- launch ----------------
extern "C" void kernel_launch(void* const* d_in, const int* in_sizes, int n_in,
                              void* d_out, int out_size, void* d_ws, size_t ws_size,
                              hipStream_t stream)
{
    (void)in_sizes; (void)n_in; (void)out_size; (void)ws_size;
    const float* x     = (const float*)d_in[0];
    const float* w3    = (const float*)d_in[1];
    const float* b3    = (const float*)d_in[2];
    const float* off3w = (const float*)d_in[3];
    const float* off3b = (const float*)d_in[4];
    const float* w5    = (const float*)d_in[5];
    const float* b5    = (const float*)d_in[6];
    const float* off5w = (const float*)d_in[7];
    const float* off5b = (const float*)d_in[8];
    const float* subw  = (const float*)d_in[9];
    const float* subb  = (const float*)d_in[10];

    unsigned short* us = (unsigned short*)d_ws;
    float* fb  = (float*)((char*)d_ws + FB_BYTES);
    float* omb = fb + F_OM;
    float* out = (float*)d_out;

    prep_kernel<<<dim3(1024), dim3(256), 0, stream>>>(
        x, w3, b3, off3w, off3b, w5, b5, off5w, off5b, subw, subb, us, fb);

    // offset conv (k3 embedded in 5x5, 102ch padded to 128) -> om buffer
    convm<false><<<dim3(98, 8, 1), dim3(256), 0, stream>>>(
        us + US_XP, nullptr, omb,
        us + US_WOFF, fb + F_BOM, us + US_WOFF, fb + F_BOM,
        5, 5, 25, 25, 0, 0, 0, 0, 128);

    // deform convs + fused sub-conv tap + bias + relu
    // z=0: k5 (26 taps) -> out ch 128..255 ; z=1: k3 (10 taps) -> out ch 0..127
    convm<true><<<dim3(98, 8, 2), dim3(256), 0, stream>>>(
        us + US_XP, omb, out,
        us + US_W5, fb + F_B5, us + US_W3, fb + F_B3,
        5, 3, 26, 10, 27, 0, 128, 0, 256);
}